// Round 1
// baseline (872.568 us; speedup 1.0000x reference)
//
#include <hip/hip_runtime.h>

// Circuit_67473936220746: 23-qubit state (2, 2^23) fp32, four 7-qubit gates.
// Index algebra (verified from the reference's perm/reshape):
//   gates 0,1,2 contract a = idx & 127          (low 7 bits)
//   gate  3     contract a = (idx >> 7) & 127   (bits 7..13)
// Per gate (channel-swapped Karatsuba):
//   ch0_out = Ur*ch1_in + Ui*ch0_in   (imag)
//   ch1_out = Ur*ch0_in - Ui*ch1_in   (real)
// => one real GEMM per gate: C[m,k'] = sum_{a'} X[m,a'] * W[k',a'],
//    k'=ch_out*128+k, a'=ch_in*128+a, W = [[Ui, Ur],[Ur, -Ui]].

static constexpr int NSTATE = 1 << 23;   // per-channel elements
static constexpr int TM     = 16;        // rows per block tile
static constexpr int CA     = 32;        // a' chunk staged per iteration
static constexpr int XPAD   = 260;       // 256 + 4: kills MID-staging bank conflicts, keeps 16B align
static constexpr int WPAD   = 36;        // 32 + 4: conflict-free strided reads, 16B align

// MODE 0: contract low 7 bits (gates 0-2). MODE 1: contract bits 7..13 (gate 3).
template<int MODE>
__global__ __launch_bounds__(256, 2)
void gate_kernel(const float* __restrict__ src, float* __restrict__ dst,
                 const float* __restrict__ Ug)   // Ug -> U[g][0][0][0]; Ui at +16384
{
    __shared__ float Xs[TM][XPAD];
    __shared__ float Ws[256][WPAD];

    const int t  = threadIdx.x;
    const int r0 = blockIdx.x * TM;

    // ---- stage X tile: rows r0..r0+TM-1, 256 a' each ----
    if (MODE == 0) {
        // row r = m; addr = ch*NSTATE + r*128 + a  (contiguous in a)
        const int ch = t >> 7, a = t & 127;
        const float* base = src + (size_t)ch * NSTATE + (size_t)r0 * 128 + a;
        #pragma unroll
        for (int m = 0; m < TM; ++m)
            Xs[m][t] = base[(size_t)m * 128];
    } else {
        // row r = hh*128 + l; addr = ch*NSTATE + hh*16384 + b*128 + l
        const int hh = r0 >> 7, l0 = r0 & 127;
        const float* base = src + (size_t)hh * 16384 + l0;
        #pragma unroll
        for (int i = 0; i < TM; ++i) {
            const int e  = i * 256 + t;
            const int dl = e & 15;            // row within tile
            const int b  = (e >> 4) & 127;    // contracted index
            const int ch = e >> 11;
            Xs[dl][ch * 128 + b] = base[(size_t)ch * NSTATE + b * 128 + dl];
        }
    }

    float acc[4][4] = {};                 // [mi][ki]
    const int kq = t & 63;                // k' lane base
    const int mg = (t >> 6) * 4;          // m group base (4 rows)
    const int j  = t & 31;                // staging column
    const int kb = t >> 5;                // staging row base (0..7)

    for (int a0 = 0; a0 < 256; a0 += CA) {
        __syncthreads();                  // also orders X staging before first use
        // ---- stage signed W chunk from U (global, L1/L2-resident) ----
        const int ch_in = a0 >> 7;
        const int acol  = (a0 & 127) + j;
        #pragma unroll
        for (int kk = 0; kk < 32; ++kk) {
            const int   kp     = kb + kk * 8;
            const int   ch_out = kp >> 7;
            const int   c      = (ch_out == ch_in) ? 1 : 0;       // pick Ui on diagonal blocks
            const float sgn    = (ch_out & ch_in) ? -1.f : 1.f;   // -Ui in (1,1) block
            Ws[kp][j] = sgn * Ug[c * 16384 + (kp & 127) * 128 + acol];
        }
        __syncthreads();
        // ---- 4x4 micro-tile FMA: 64 FMA per 8 ds_read_b128 ----
        #pragma unroll
        for (int j4 = 0; j4 < CA / 4; ++j4) {
            float4 w[4], x[4];
            #pragma unroll
            for (int i = 0; i < 4; ++i)
                w[i] = *(const float4*)&Ws[kq + i * 64][j4 * 4];
            #pragma unroll
            for (int i = 0; i < 4; ++i)
                x[i] = *(const float4*)&Xs[mg + i][a0 + j4 * 4];
            #pragma unroll
            for (int mi = 0; mi < 4; ++mi)
                #pragma unroll
                for (int ki = 0; ki < 4; ++ki)
                    acc[mi][ki] += w[ki].x * x[mi].x + w[ki].y * x[mi].y
                                 + w[ki].z * x[mi].z + w[ki].w * x[mi].w;
        }
    }

    // ---- epilogue: in-place safe (block writes exactly the rows it staged) ----
    if (MODE == 0) {
        #pragma unroll
        for (int mi = 0; mi < 4; ++mi) {
            float* row = dst + (size_t)(r0 + mg + mi) * 128;
            #pragma unroll
            for (int ki = 0; ki < 4; ++ki) {
                const int kp = kq + ki * 64;
                row[(size_t)(kp >> 7) * NSTATE + (kp & 127)] = acc[mi][ki];
            }
        }
    } else {
        const int hh = r0 >> 7, l0 = r0 & 127;
        float* base = dst + (size_t)hh * 16384 + l0;
        #pragma unroll
        for (int mi = 0; mi < 4; ++mi) {
            #pragma unroll
            for (int ki = 0; ki < 4; ++ki) {
                const int kp = kq + ki * 64;
                base[(size_t)(kp >> 7) * NSTATE + (size_t)(kp & 127) * 128 + (mg + mi)] = acc[mi][ki];
            }
        }
    }
}

extern "C" void kernel_launch(void* const* d_in, const int* in_sizes, int n_in,
                              void* d_out, int out_size, void* d_ws, size_t ws_size,
                              hipStream_t stream) {
    const float* state = (const float*)d_in[0];   // (2, 2^23)
    const float* U     = (const float*)d_in[1];   // (4, 2, 128, 128)
    float* out = (float*)d_out;

    const dim3 grid(65536 / TM), block(256);
    // gate 0: d_in -> d_out; gates 1-3: in-place on d_out
    gate_kernel<0><<<grid, block, 0, stream>>>(state, out, U + 0 * 32768);
    gate_kernel<0><<<grid, block, 0, stream>>>(out,   out, U + 1 * 32768);
    gate_kernel<0><<<grid, block, 0, stream>>>(out,   out, U + 2 * 32768);
    gate_kernel<1><<<grid, block, 0, stream>>>(out,   out, U + 3 * 32768);
}

// Round 2
// 212.901 us; speedup vs baseline: 4.0985x; 4.0985x over previous
//
#include <hip/hip_runtime.h>

// Circuit_67473936220746, round 2: composed gates + bf16 MFMA (3-term split).
//
// Algebra: state viewed as X[65536 rows][256 cols] per pass.
//   Gates 0,1,2 contract a' = ch*128 + (idx & 127)      -> one composed matrix
//       WA = W2*W1*W0 (each Wg = [[Ui,Ur],[Ur,-Ui]], 256x256)
//   Gate 3 contracts a' = ch*128 + ((idx>>7) & 127)     -> WB = W3
//   Each pass: X <- X * W^T, computed as C[m][kp] = sum_ap X[m][ap]*W[kp][ap].
//
// Precision: fp32 -> (hi,lo) bf16 split; C ~= Xh*Wh + Xl*Wh + Xh*Wl
// (drops Xl*Wl ~ 2^-18 rel). Composition done in exact fp32 on device.
//
// MFMA 16x16x32 bf16 layouts (HW-verified per guide):
//   A: lane&15 = m,  k = (lane>>4)*8 + j   (8 contiguous bf16 = 16B/lane)
//   B: lane&15 = n,  k = (lane>>4)*8 + j
//   C/D: col = lane&15, row = (lane>>4)*4 + reg

typedef __attribute__((ext_vector_type(8))) short bf16x8;
typedef __attribute__((ext_vector_type(4))) float f32x4;

static constexpr int NSTATE = 1 << 23;   // per-channel elements

__device__ inline void bf16_split(float x, unsigned short& h, unsigned short& l) {
    union { float f; unsigned int u; } a; a.f = x;
    unsigned int r = (a.u + 0x7FFFu + ((a.u >> 16) & 1u)) >> 16;   // RNE to bf16
    h = (unsigned short)r;
    union { unsigned int u; float f; } b; b.u = r << 16;
    union { float f; unsigned int u; } c; c.f = x - b.f;
    unsigned int r2 = (c.u + 0x7FFFu + ((c.u >> 16) & 1u)) >> 16;
    l = (unsigned short)r2;
}

// ---- prep: assemble signed 256x256 W_g from U[g] (fp32) ----
__global__ void assemble_W(const float* __restrict__ U, float* __restrict__ W) {
    const int g  = blockIdx.y;
    const int kp = blockIdx.x, ap = threadIdx.x;
    const int co = kp >> 7, ci = ap >> 7;
    const int c  = (co == ci) ? 1 : 0;              // Ui on diagonal blocks
    const float sgn = (co & ci) ? -1.f : 1.f;       // -Ui in (1,1)
    W[(size_t)g * 65536 + kp * 256 + ap] =
        sgn * U[(size_t)g * 32768 + c * 16384 + (kp & 127) * 128 + (ap & 127)];
}

// ---- prep: C = A*B, 256x256x256 fp32 ----
__global__ void matmul256(const float* __restrict__ A, const float* __restrict__ B,
                          float* __restrict__ C) {
    const int i = blockIdx.x, j = threadIdx.x;
    float s = 0.f;
    for (int t = 0; t < 256; ++t) s = fmaf(A[i * 256 + t], B[t * 256 + j], s);
    C[i * 256 + j] = s;
}

// ---- prep: split fp32 matrix -> bf16 hi/lo ----
__global__ void split_bf16(const float* __restrict__ Wf, unsigned short* __restrict__ Wh,
                           unsigned short* __restrict__ Wl) {
    const int idx = blockIdx.x * 256 + threadIdx.x;
    bf16_split(Wf[idx], Wh[idx], Wl[idx]);
}

// ---- main GEMM pass: 64m x 256n per block, 4 waves of 64m x 64n, K=256 ----
// MODE 0: contract low 7 bits (composed gates 0-2). MODE 1: contract bits 7..13.
template<int MODE>
__global__ __launch_bounds__(256, 2)
void gemm_pass(const float* __restrict__ src, float* __restrict__ dst,
               const unsigned short* __restrict__ Wh, const unsigned short* __restrict__ Wl)
{
    __shared__ __align__(16) unsigned short Ah[4][64][8];  // [mt][lane][j], frag order
    __shared__ __align__(16) unsigned short Al[4][64][8];

    const int t    = threadIdx.x;
    const int lane = t & 63;
    const int w    = t >> 6;           // wave id -> n range [w*64, w*64+64)
    const int m0   = blockIdx.x * 64;

    f32x4 acc[4][4];
    #pragma unroll
    for (int i = 0; i < 4; ++i)
        #pragma unroll
        for (int j = 0; j < 4; ++j) acc[i][j] = (f32x4)0.f;

    for (int a0 = 0; a0 < 256; a0 += 32) {
        __syncthreads();
        // ---- stage X chunk (64 rows x 32 a'), split to bf16 hi/lo in frag order ----
        float xv[8];
        int mt, ld;
        if (MODE == 0) {
            const int m = t >> 2, k0 = (t & 3) * 8;     // 8 consecutive a'
            const int ch = a0 >> 7;
            const float* p = src + (size_t)ch * NSTATE + (size_t)(m0 + m) * 128
                           + (a0 & 127) + k0;
            float4 x0 = *(const float4*)p;
            float4 x1 = *(const float4*)(p + 4);
            xv[0]=x0.x; xv[1]=x0.y; xv[2]=x0.z; xv[3]=x0.w;
            xv[4]=x1.x; xv[5]=x1.y; xv[6]=x1.z; xv[7]=x1.w;
            mt = m >> 4; ld = (m & 15) + 16 * (t & 3);
        } else {
            const int l = t & 63, kg = t >> 6;          // row offset l, k-group kg
            const int ch = a0 >> 7;
            const int h = m0 >> 7, l0 = m0 & 127;
            const float* p = src + (size_t)ch * NSTATE + (size_t)h * 16384
                           + (size_t)((a0 & 127) + kg * 8) * 128 + l0 + l;
            #pragma unroll
            for (int i = 0; i < 8; ++i) xv[i] = p[(size_t)i * 128];
            mt = l >> 4; ld = (l & 15) + 16 * kg;
        }
        bf16x8 hv, lv;
        #pragma unroll
        for (int i = 0; i < 8; ++i) {
            unsigned short hh, ll;
            bf16_split(xv[i], hh, ll);
            hv[i] = (short)hh; lv[i] = (short)ll;
        }
        *(bf16x8*)&Ah[mt][ld][0] = hv;
        *(bf16x8*)&Al[mt][ld][0] = lv;
        __syncthreads();

        // ---- A frags from LDS (conflict-free, lane-linear) ----
        bf16x8 ah[4], al[4];
        #pragma unroll
        for (int i = 0; i < 4; ++i) {
            ah[i] = *(const bf16x8*)&Ah[i][lane][0];
            al[i] = *(const bf16x8*)&Al[i][lane][0];
        }
        // ---- B frags direct from L2; 48 MFMA per k-step per wave ----
        const int ap = a0 + (lane >> 4) * 8;
        #pragma unroll
        for (int nt = 0; nt < 4; ++nt) {
            const int kp = w * 64 + nt * 16 + (lane & 15);
            bf16x8 bh = *(const bf16x8*)(Wh + kp * 256 + ap);
            bf16x8 bl = *(const bf16x8*)(Wl + kp * 256 + ap);
            #pragma unroll
            for (int mi = 0; mi < 4; ++mi) {
                acc[mi][nt] = __builtin_amdgcn_mfma_f32_16x16x32_bf16(ah[mi], bh, acc[mi][nt], 0, 0, 0);
                acc[mi][nt] = __builtin_amdgcn_mfma_f32_16x16x32_bf16(al[mi], bh, acc[mi][nt], 0, 0, 0);
                acc[mi][nt] = __builtin_amdgcn_mfma_f32_16x16x32_bf16(ah[mi], bl, acc[mi][nt], 0, 0, 0);
            }
        }
    }

    // ---- epilogue (in-place safe: block writes exactly the rows it read) ----
    const int quad = lane >> 4, col = lane & 15;
    #pragma unroll
    for (int mi = 0; mi < 4; ++mi) {
        #pragma unroll
        for (int nt = 0; nt < 4; ++nt) {
            #pragma unroll
            for (int r = 0; r < 4; ++r) {
                const int m_loc = mi * 16 + quad * 4 + r;
                const int n     = w * 64 + nt * 16 + col;   // k' = ch_out*128 + k
                if (MODE == 0) {
                    dst[(size_t)(n >> 7) * NSTATE + (size_t)(m0 + m_loc) * 128 + (n & 127)]
                        = acc[mi][nt][r];
                } else {
                    dst[(size_t)(n >> 7) * NSTATE + (size_t)(m0 >> 7) * 16384
                        + (size_t)(n & 127) * 128 + (m0 & 127) + m_loc]
                        = acc[mi][nt][r];
                }
            }
        }
    }
}

extern "C" void kernel_launch(void* const* d_in, const int* in_sizes, int n_in,
                              void* d_out, int out_size, void* d_ws, size_t ws_size,
                              hipStream_t stream) {
    const float* state = (const float*)d_in[0];   // (2, 2^23)
    const float* U     = (const float*)d_in[1];   // (4, 2, 128, 128)
    float* out = (float*)d_out;

    // ws layout (2 MB total): 6 fp32 256x256 matrices + 4 bf16 256x256 matrices
    float* W0 = (float*)d_ws;          // assembled W_g, g=0..3 at W0+g*65536
    float* T  = W0 + 4 * 65536;
    float* WA = W0 + 5 * 65536;
    unsigned short* WAh = (unsigned short*)(W0 + 6 * 65536);
    unsigned short* WAl = WAh + 65536;
    unsigned short* WBh = WAh + 2 * 65536;
    unsigned short* WBl = WAh + 3 * 65536;

    assemble_W<<<dim3(256, 4), 256, 0, stream>>>(U, W0);
    matmul256<<<256, 256, 0, stream>>>(W0 + 65536, W0, T);        // T  = W1*W0
    matmul256<<<256, 256, 0, stream>>>(W0 + 2 * 65536, T, WA);    // WA = W2*T
    split_bf16<<<256, 256, 0, stream>>>(WA, WAh, WAl);
    split_bf16<<<256, 256, 0, stream>>>(W0 + 3 * 65536, WBh, WBl);

    gemm_pass<0><<<1024, 256, 0, stream>>>(state, out, WAh, WAl); // gates 0-2
    gemm_pass<1><<<1024, 256, 0, stream>>>(out,   out, WBh, WBl); // gate 3
}